// Round 1
// baseline (381.537 us; speedup 1.0000x reference)
//
#include <hip/hip_runtime.h>
#include <hip/hip_bf16.h>

#define NN 50000
#define EE 850000
#define NBLK_SCAN 98  // ceil(50000/512)

typedef unsigned short u16;
using short8 = __attribute__((ext_vector_type(8))) short;
using f32x4  = __attribute__((ext_vector_type(4))) float;

__device__ __forceinline__ float bf2f(u16 u) {
    union { unsigned int i; float f; } v; v.i = ((unsigned int)u) << 16; return v.f;
}
__device__ __forceinline__ u16 f2bf(float f) {
    __hip_bfloat16 h = __float2bfloat16(f);
    return *reinterpret_cast<u16*>(&h);
}

__device__ __forceinline__ float ld1(const void* X, size_t i, bool f32m) {
    return f32m ? ((const float*)X)[i] : bf2f(((const u16*)X)[i]);
}
__device__ __forceinline__ void load4(const void* X, size_t g, bool f32m, float o[4]) {
    if (f32m) {
        float4 v = ((const float4*)X)[g];
        o[0] = v.x; o[1] = v.y; o[2] = v.z; o[3] = v.w;
    } else {
        ushort4 v = ((const ushort4*)X)[g];
        o[0] = bf2f(v.x); o[1] = bf2f(v.y); o[2] = bf2f(v.z); o[3] = bf2f(v.w);
    }
}

// ---- block 0: dtype detect; blocks 1..196: zero deg ----
__global__ void k_detect(const u16* __restrict__ hh, int* __restrict__ flag,
                         int* __restrict__ deg) {
    if (blockIdx.x != 0) {
        int i = (blockIdx.x - 1) * 256 + threadIdx.x;
        if (i < NN) deg[i] = 0;
        return;
    }
    __shared__ int sm[256];
    int t = threadIdx.x;
    int c = 0;
    for (int i = 0; i < 16; ++i) {
        u16 u = hh[t * 16 + i];
        int e = (u >> 7) & 0xFF;
        if (e != 0 && (e < 90 || e > 160)) ++c;
    }
    sm[t] = c;
    __syncthreads();
    for (int s = 128; s > 0; s >>= 1) {
        if (t < s) sm[t] += sm[t + s];
        __syncthreads();
    }
    if (t == 0) *flag = (sm[0] > 200) ? 1 : 0;
}

// ---- fused prep: 0..511 B-transpose, 512..527 attn vecs, rest deg+rank ----
__global__ void k_prep(const void* __restrict__ W1s, const void* __restrict__ al1,
                       const void* __restrict__ W1d, const void* __restrict__ ar1,
                       const void* __restrict__ W2s, const void* __restrict__ al2,
                       const void* __restrict__ W2d, const void* __restrict__ ar2,
                       const void* __restrict__ Wres2, const int* __restrict__ dst,
                       u16* __restrict__ BT1, u16* __restrict__ BT2,
                       float* __restrict__ wl1, float* __restrict__ wr1,
                       float* __restrict__ wl2, float* __restrict__ wr2,
                       int* __restrict__ deg, int* __restrict__ eorder,
                       const int* __restrict__ mode) {
    int bid = blockIdx.x;
    if (bid >= 528) {
        int e = (bid - 528) * 256 + threadIdx.x;
        if (e < EE) {
            int r = atomicAdd(&deg[dst[e]], 1);
            eorder[e] = r;
        }
        return;
    }
    bool f32m = (*mode) != 0;
    if (bid < 512) {
        int id = bid * 256 + threadIdx.x;  // 0..131071
        int which = id >> 16;
        int rem = id & 65535;
        int n = rem >> 8, k = rem & 255;
        if (which == 0) {
            BT1[n * 256 + k] = f2bf(ld1(W1s, (size_t)k * 256 + n, f32m));
        } else {
            float v = (n < 128) ? ld1(W2s, (size_t)k * 128 + n, f32m)
                                : ld1(Wres2, (size_t)k * 128 + (n - 128), f32m);
            BT2[n * 256 + k] = f2bf(v);
        }
    } else {
        int id = (bid - 512) * 256 + threadIdx.x;  // 0..4095
        int which = id >> 10;
        int rem = id & 1023;
        int k = rem >> 2, h = rem & 3;
        float s = 0.f;
        if (which == 0) {
            for (int d = 0; d < 64; ++d) s += ld1(W1s, k * 256 + h * 64 + d, f32m) * ld1(al1, h * 64 + d, f32m);
            wl1[k * 4 + h] = s;
        } else if (which == 1) {
            for (int d = 0; d < 64; ++d) s += ld1(W1d, k * 256 + h * 64 + d, f32m) * ld1(ar1, h * 64 + d, f32m);
            wr1[k * 4 + h] = s;
        } else if (which == 2) {
            for (int d = 0; d < 32; ++d) s += ld1(W2s, k * 128 + h * 32 + d, f32m) * ld1(al2, h * 32 + d, f32m);
            wl2[k * 4 + h] = s;
        } else {
            for (int d = 0; d < 32; ++d) s += ld1(W2d, k * 128 + h * 32 + d, f32m) * ld1(ar2, h * 32 + d, f32m);
            wr2[k * 4 + h] = s;
        }
    }
}

// ---- CSR scan stage 1: per-block inclusive scan + block sums ----
__global__ void k_scan1(const int* __restrict__ deg, int* __restrict__ rowptr,
                        int* __restrict__ bsum) {
    __shared__ int sm[512];
    int t = threadIdx.x;
    int i = blockIdx.x * 512 + t;
    int v = (i < NN) ? deg[i] : 0;
    int x = v;
    sm[t] = x;
    __syncthreads();
    for (int off = 1; off < 512; off <<= 1) {
        int y = (t >= off) ? sm[t - off] : 0;
        __syncthreads();
        x += y;
        sm[t] = x;
        __syncthreads();
    }
    if (i < NN) rowptr[i] = x - v;
    if (t == 511) bsum[blockIdx.x] = x;
}

// ---- fused: blocks 0..195 scan-finalize (inline bsum prefix); rest eler1 ----
__global__ void k_scan3_eler1(int* __restrict__ rowptr, const int* __restrict__ bsum,
                              const void* __restrict__ X,
                              const float* __restrict__ wl, const float* __restrict__ wr,
                              float* __restrict__ el, float* __restrict__ er,
                              const int* __restrict__ mode) {
    int bid = blockIdx.x;
    if (bid < 196) {
        __shared__ int sm[NBLK_SCAN];
        int t = threadIdx.x;
        if (t < NBLK_SCAN) sm[t] = bsum[t];
        __syncthreads();
        int g = bid >> 1;  // each block's 256 indices lie in one 512-group
        int pre = 0;
        for (int j = 0; j < g; ++j) pre += sm[j];  // LDS broadcast, uniform
        int i = bid * 256 + t;
        if (i < NN) {
            rowptr[i] += pre;
            if (i == 0) rowptr[NN] = EE;
        }
        return;
    }
    bool f32m = (*mode) != 0;
    int wave = threadIdx.x >> 6, lane = threadIdx.x & 63;
    int node = (bid - 196) * 4 + wave;
    float a[4];
    load4(X, (size_t)node * 64 + lane, f32m, a);
    float accl[4] = {0, 0, 0, 0}, accr[4] = {0, 0, 0, 0};
    int k0 = lane * 4;
#pragma unroll
    for (int j = 0; j < 4; ++j) {
        float4 wlv = ((const float4*)wl)[k0 + j];
        float4 wrv = ((const float4*)wr)[k0 + j];
        accl[0] += a[j] * wlv.x; accl[1] += a[j] * wlv.y;
        accl[2] += a[j] * wlv.z; accl[3] += a[j] * wlv.w;
        accr[0] += a[j] * wrv.x; accr[1] += a[j] * wrv.y;
        accr[2] += a[j] * wrv.z; accr[3] += a[j] * wrv.w;
    }
#pragma unroll
    for (int off = 32; off > 0; off >>= 1) {
#pragma unroll
        for (int t = 0; t < 4; ++t) {
            accl[t] += __shfl_down(accl[t], off, 64);
            accr[t] += __shfl_down(accr[t], off, 64);
        }
    }
    if (lane == 0) {
        float4 vl = {accl[0], accl[1], accl[2], accl[3]};
        float4 vr = {accr[0], accr[1], accr[2], accr[3]};
        ((float4*)el)[node] = vl;
        ((float4*)er)[node] = vr;
    }
}

// ---- edge-parallel weight gen (atomic-free): slot = rowptr[d]+eorder[e] ----
__global__ void k_awgen(const int* __restrict__ src, const int* __restrict__ dst,
                        const int* __restrict__ eorder, const int* __restrict__ rowptr,
                        const float* __restrict__ el, const float* __restrict__ er,
                        u16* __restrict__ aw, int* __restrict__ csrc, int writeCsrc) {
    int e = blockIdx.x * 256 + threadIdx.x;
    if (e >= EE) return;
    int s = src[e], d = dst[e];
    int slot = rowptr[d] + eorder[e];
    if (writeCsrc) csrc[slot] = s;
    float4 eL = ((const float4*)el)[s];
    float4 eR = ((const float4*)er)[d];
    float ev[4] = {eL.x + eR.x, eL.y + eR.y, eL.z + eR.z, eL.w + eR.w};
    ushort4 o;
    u16* op = (u16*)&o;
#pragma unroll
    for (int t = 0; t < 4; ++t) {
        float x = ev[t];
        x = x > 0.f ? x : 0.2f * x;
        x = fminf(fmaxf(x, -60.f), 60.f);
        op[t] = f2bf(__expf(x));
    }
    ((ushort4*)aw)[slot] = o;
}

// ---- MFMA GEMM: C[M][256] bf16 = A[M][256] @ B (BT transposed [256n][256k]) ----
__global__ void k_gemm_mfma(const void* __restrict__ A, int aDual,
                            const u16* __restrict__ BT, u16* __restrict__ C,
                            const int* __restrict__ mode) {
    bool af32 = aDual && ((*mode) != 0);
    __shared__ u16 At[128 * 72];
    __shared__ u16 Bt[128 * 72];
    int t = threadIdx.x;
    int lane = t & 63, w = t >> 6;
    int mt = blockIdx.x >> 1, nt = blockIdx.x & 1;
    int m0 = mt * 128, n0 = nt * 128;
    int wr = (w >> 1) * 64, wc = (w & 1) * 64;
    f32x4 acc[4][4] = {};
    int q = lane >> 4, cl = lane & 15;

    for (int ph = 0; ph < 4; ++ph) {
        int kb = ph * 64;
        for (int it = 0; it < 4; ++it) {
            int c = it * 256 + t;
            int row = c >> 3, c8 = c & 7;
            int rowg = m0 + row;
            if (af32) {
                if (rowg < NN) {
                    const float* ap = (const float*)A + (size_t)rowg * 256 + kb + c8 * 8;
                    float4 v0 = ((const float4*)ap)[0];
                    float4 v1 = ((const float4*)ap)[1];
                    ushort4 lo = {f2bf(v0.x), f2bf(v0.y), f2bf(v0.z), f2bf(v0.w)};
                    ushort4 hi = {f2bf(v1.x), f2bf(v1.y), f2bf(v1.z), f2bf(v1.w)};
                    *(ushort4*)&At[row * 72 + c8 * 8] = lo;
                    *(ushort4*)&At[row * 72 + c8 * 8 + 4] = hi;
                } else {
                    ushort4 z = {0, 0, 0, 0};
                    *(ushort4*)&At[row * 72 + c8 * 8] = z;
                    *(ushort4*)&At[row * 72 + c8 * 8 + 4] = z;
                }
            } else {
                float4 av;
                if (rowg < NN) {
                    av = *(const float4*)((const u16*)A + (size_t)rowg * 256 + kb + c8 * 8);
                } else {
                    av = make_float4(0.f, 0.f, 0.f, 0.f);
                }
                *(float4*)&At[row * 72 + c8 * 8] = av;
            }
            float4 bv = *(const float4*)(BT + (size_t)(n0 + row) * 256 + kb + c8 * 8);
            *(float4*)&Bt[row * 72 + c8 * 8] = bv;
        }
        __syncthreads();
#pragma unroll
        for (int ks = 0; ks < 2; ++ks) {
            short8 af[4], bf[4];
#pragma unroll
            for (int i = 0; i < 4; ++i)
                af[i] = *(const short8*)&At[(wr + i * 16 + cl) * 72 + ks * 32 + q * 8];
#pragma unroll
            for (int j = 0; j < 4; ++j)
                bf[j] = *(const short8*)&Bt[(wc + j * 16 + cl) * 72 + ks * 32 + q * 8];
#pragma unroll
            for (int i = 0; i < 4; ++i)
#pragma unroll
                for (int j = 0; j < 4; ++j)
                    acc[i][j] = __builtin_amdgcn_mfma_f32_16x16x32_bf16(af[i], bf[j], acc[i][j], 0, 0, 0);
        }
        __syncthreads();
    }
#pragma unroll
    for (int i = 0; i < 4; ++i)
#pragma unroll
        for (int j = 0; j < 4; ++j)
#pragma unroll
            for (int r = 0; r < 4; ++r) {
                int mrow = m0 + wr + i * 16 + q * 4 + r;
                if (mrow < NN)
                    C[(size_t)mrow * 256 + n0 + wc + j * 16 + cl] = f2bf(acc[i][j][r]);
            }
}

// ---- layer-1 aggregation: wide-gather (2 edges per dwordx4 instr) + fused eler2 ----
// Per wave: lanes split as (half = lane>>5) edge-parity, (cl = lane&31) col-group.
// csrc/aw preloaded lane-parallel per 64-edge chunk, distributed via shuffles:
// removes 2 of the 3 per-edge VMEM instructions; gather widened 8B->16B/lane.
__global__ void k_agg1(const int* __restrict__ rowptr, const int* __restrict__ csrc,
                       const u16* __restrict__ aw, const u16* __restrict__ fs,
                       const void* __restrict__ h_in, u16* __restrict__ h1,
                       const float* __restrict__ wl2, const float* __restrict__ wr2,
                       float* __restrict__ el2, float* __restrict__ er2,
                       const int* __restrict__ mode) {
    bool f32m = (*mode) != 0;
    int wave = threadIdx.x >> 6, lane = threadIdx.x & 63;
    int node = blockIdx.x * 4 + wave;
    int beg = rowptr[node], end = rowptr[node + 1];
    int half = lane >> 5;    // which edge of the pair this lane works on
    int cl = lane & 31;      // owns cols cl*8 .. cl*8+7
    int head = cl >> 3;      // head of owned cols
    uint hsel2 = head & 2, hsel1 = head & 1;
    float acc[8] = {0, 0, 0, 0, 0, 0, 0, 0};
    float ll = 0.f;
    for (int cb = beg; cb < end; cb += 64) {
        int nedge = end - cb;
        if (nedge > 64) nedge = 64;
        int s_l = 0;
        uint wx_l = 0, wy_l = 0;
        if (lane < nedge) {
            s_l = csrc[cb + lane];
            uint2 wv = ((const uint2*)aw)[cb + lane];
            wx_l = wv.x; wy_l = wv.y;
        }
#pragma unroll 4
        for (int j = 0; j < nedge; j += 2) {
            int e = j + half;
            int s = __shfl(s_l, e, 64);
            uint wx = (uint)__shfl((int)wx_l, e, 64);
            uint wy = (uint)__shfl((int)wy_l, e, 64);
            uint uu = hsel2 ? wy : wx;
            uint pb = hsel1 ? (uu & 0xffff0000u) : (uu << 16);
            float pw = (e < nedge) ? __uint_as_float(pb) : 0.f;
            uint4 fv = *(const uint4*)(fs + (size_t)s * 256 + cl * 8);
            ll += pw;
            acc[0] += pw * __uint_as_float(fv.x << 16);
            acc[1] += pw * __uint_as_float(fv.x & 0xffff0000u);
            acc[2] += pw * __uint_as_float(fv.y << 16);
            acc[3] += pw * __uint_as_float(fv.y & 0xffff0000u);
            acc[4] += pw * __uint_as_float(fv.z << 16);
            acc[5] += pw * __uint_as_float(fv.z & 0xffff0000u);
            acc[6] += pw * __uint_as_float(fv.w << 16);
            acc[7] += pw * __uint_as_float(fv.w & 0xffff0000u);
        }
    }
    // combine the two edge-parity halves (lane l <-> l^32 hold the same cols)
#pragma unroll
    for (int k = 0; k < 8; ++k) acc[k] += __shfl_xor(acc[k], 32, 64);
    ll += __shfl_xor(ll, 32, 64);
    float rinv = 1.f / ll;
    int q = (cl << 1) | half;  // bijection of lane; owns output cols q*4 .. q*4+3
    float res[4];
    load4(h_in, (size_t)node * 64 + q, f32m, res);
    float v0 = acc[half * 4 + 0] * rinv + res[0];
    float v1 = acc[half * 4 + 1] * rinv + res[1];
    float v2 = acc[half * 4 + 2] * rinv + res[2];
    float v3 = acc[half * 4 + 3] * rinv + res[3];
    v0 = v0 > 0.f ? v0 : __expf(v0) - 1.f;
    v1 = v1 > 0.f ? v1 : __expf(v1) - 1.f;
    v2 = v2 > 0.f ? v2 : __expf(v2) - 1.f;
    v3 = v3 > 0.f ? v3 : __expf(v3) - 1.f;
    ushort4 o = {f2bf(v0), f2bf(v1), f2bf(v2), f2bf(v3)};
    ((ushort4*)h1)[(size_t)node * 64 + q] = o;
    // fused eler2: this lane owns h1 cols q*4..q*4+3
    float4 w0 = ((const float4*)wl2)[q * 4 + 0];
    float4 w1 = ((const float4*)wl2)[q * 4 + 1];
    float4 w2 = ((const float4*)wl2)[q * 4 + 2];
    float4 w3 = ((const float4*)wl2)[q * 4 + 3];
    float4 r0 = ((const float4*)wr2)[q * 4 + 0];
    float4 r1 = ((const float4*)wr2)[q * 4 + 1];
    float4 r2 = ((const float4*)wr2)[q * 4 + 2];
    float4 r3 = ((const float4*)wr2)[q * 4 + 3];
    float acl[4], acr[4];
    acl[0] = v0 * w0.x + v1 * w1.x + v2 * w2.x + v3 * w3.x;
    acl[1] = v0 * w0.y + v1 * w1.y + v2 * w2.y + v3 * w3.y;
    acl[2] = v0 * w0.z + v1 * w1.z + v2 * w2.z + v3 * w3.z;
    acl[3] = v0 * w0.w + v1 * w1.w + v2 * w2.w + v3 * w3.w;
    acr[0] = v0 * r0.x + v1 * r1.x + v2 * r2.x + v3 * r3.x;
    acr[1] = v0 * r0.y + v1 * r1.y + v2 * r2.y + v3 * r3.y;
    acr[2] = v0 * r0.z + v1 * r1.z + v2 * r2.z + v3 * r3.z;
    acr[3] = v0 * r0.w + v1 * r1.w + v2 * r2.w + v3 * r3.w;
#pragma unroll
    for (int off = 32; off > 0; off >>= 1) {
#pragma unroll
        for (int t = 0; t < 4; ++t) {
            acl[t] += __shfl_down(acl[t], off, 64);
            acr[t] += __shfl_down(acr[t], off, 64);
        }
    }
    if (lane == 0) {
        float4 vl = {acl[0], acl[1], acl[2], acl[3]};
        float4 vr = {acr[0], acr[1], acr[2], acr[3]};
        ((float4*)el2)[node] = vl;
        ((float4*)er2)[node] = vr;
    }
}

// ---- layer-2 aggregation: wide-gather (4 edges per dwordx4 instr) + residual + head-mean ----
__global__ void k_agg2(const int* __restrict__ rowptr, const int* __restrict__ csrc,
                       const u16* __restrict__ aw, const u16* __restrict__ c2,
                       void* __restrict__ out, const int* __restrict__ mode) {
    bool f32m = (*mode) != 0;
    int wave = threadIdx.x >> 6, lane = threadIdx.x & 63;
    int node = blockIdx.x * 4 + wave;
    int beg = rowptr[node], end = rowptr[node + 1];
    int quarter = lane >> 4;  // which edge of the quad
    int cq = lane & 15;       // owns cols cq*8 .. cq*8+7 (of 128)
    int head = cq >> 2;
    uint hsel2 = head & 2, hsel1 = head & 1;
    float acc[8] = {0, 0, 0, 0, 0, 0, 0, 0};
    float ll = 0.f;
    for (int cb = beg; cb < end; cb += 64) {
        int nedge = end - cb;
        if (nedge > 64) nedge = 64;
        int s_l = 0;
        uint wx_l = 0, wy_l = 0;
        if (lane < nedge) {
            s_l = csrc[cb + lane];
            uint2 wv = ((const uint2*)aw)[cb + lane];
            wx_l = wv.x; wy_l = wv.y;
        }
#pragma unroll 2
        for (int j = 0; j < nedge; j += 4) {
            int e = j + quarter;
            int s = __shfl(s_l, e, 64);
            uint wx = (uint)__shfl((int)wx_l, e, 64);
            uint wy = (uint)__shfl((int)wy_l, e, 64);
            uint uu = hsel2 ? wy : wx;
            uint pb = hsel1 ? (uu & 0xffff0000u) : (uu << 16);
            float pw = (e < nedge) ? __uint_as_float(pb) : 0.f;
            uint4 fv = *(const uint4*)(c2 + (size_t)s * 256 + cq * 8);
            ll += pw;
            acc[0] += pw * __uint_as_float(fv.x << 16);
            acc[1] += pw * __uint_as_float(fv.x & 0xffff0000u);
            acc[2] += pw * __uint_as_float(fv.y << 16);
            acc[3] += pw * __uint_as_float(fv.y & 0xffff0000u);
            acc[4] += pw * __uint_as_float(fv.z << 16);
            acc[5] += pw * __uint_as_float(fv.z & 0xffff0000u);
            acc[6] += pw * __uint_as_float(fv.w << 16);
            acc[7] += pw * __uint_as_float(fv.w & 0xffff0000u);
        }
    }
    // combine the 4 edge-parity quarters (lanes with equal cq)
#pragma unroll
    for (int k = 0; k < 8; ++k) {
        acc[k] += __shfl_xor(acc[k], 16, 64);
        acc[k] += __shfl_xor(acc[k], 32, 64);
    }
    ll += __shfl_xor(ll, 16, 64);
    ll += __shfl_xor(ll, 32, 64);
    float rinv = 1.f / ll;
    // residual: cols 128 + cq*8 .. +7 of this node's row
    uint4 rv = *(const uint4*)(c2 + (size_t)node * 256 + 128 + cq * 8);
    float m[8];
    m[0] = acc[0] * rinv + __uint_as_float(rv.x << 16);
    m[1] = acc[1] * rinv + __uint_as_float(rv.x & 0xffff0000u);
    m[2] = acc[2] * rinv + __uint_as_float(rv.y << 16);
    m[3] = acc[3] * rinv + __uint_as_float(rv.y & 0xffff0000u);
    m[4] = acc[4] * rinv + __uint_as_float(rv.z << 16);
    m[5] = acc[5] * rinv + __uint_as_float(rv.z & 0xffff0000u);
    m[6] = acc[6] * rinv + __uint_as_float(rv.w << 16);
    m[7] = acc[7] * rinv + __uint_as_float(rv.w & 0xffff0000u);
    // head-mean: col = h*32 + d, h = cq>>2; sum over cq bits 2,3 then *0.25
#pragma unroll
    for (int k = 0; k < 8; ++k) {
        m[k] += __shfl_xor(m[k], 4, 64);
        m[k] += __shfl_xor(m[k], 8, 64);
        m[k] *= 0.25f;
    }
    if (lane < 4) {  // quarter==0, cq<4: owns out d = cq*8 .. +7
        size_t ob = (size_t)node * 32 + (size_t)cq * 8;
        if (f32m) {
            float4 o0 = {m[0], m[1], m[2], m[3]};
            float4 o1 = {m[4], m[5], m[6], m[7]};
            *(float4*)((float*)out + ob) = o0;
            *(float4*)((float*)out + ob + 4) = o1;
        } else {
            ushort4 o0 = {f2bf(m[0]), f2bf(m[1]), f2bf(m[2]), f2bf(m[3])};
            ushort4 o1 = {f2bf(m[4]), f2bf(m[5]), f2bf(m[6]), f2bf(m[7])};
            *(ushort4*)((u16*)out + ob) = o0;
            *(ushort4*)((u16*)out + ob + 4) = o1;
        }
    }
}

extern "C" void kernel_launch(void* const* d_in, const int* in_sizes, int n_in,
                              void* d_out, int out_size, void* d_ws, size_t ws_size,
                              hipStream_t stream) {
    int ih = 0, isrc = 1, idst = 2, iW1s = 3, iW1d = 4, ial1 = 5, iar1 = 6,
        iW2s = 7, iW2d = 8, ial2 = 9, iar2 = 10, iWres = 11;
    if (n_in >= 12 && in_sizes[0] != 12800000) {
        iW1d = 0; iW1s = 1; iW2d = 2; iW2s = 3; iWres = 4; ial1 = 5; ial2 = 6;
        iar1 = 7; iar2 = 8; idst = 9; ih = 10; isrc = 11;
    }
    const void* h     = d_in[ih];
    const int* src    = (const int*)d_in[isrc];
    const int* dst    = (const int*)d_in[idst];
    const void* W1s   = d_in[iW1s];
    const void* W1d   = d_in[iW1d];
    const void* al1   = d_in[ial1];
    const void* ar1   = d_in[iar1];
    const void* W2s   = d_in[iW2s];
    const void* W2d   = d_in[iW2d];
    const void* al2   = d_in[ial2];
    const void* ar2   = d_in[iar2];
    const void* Wres2 = d_in[iWres];

    char* w = (char*)d_ws;
    size_t off = 0;
    auto alloc = [&](size_t bytes) -> void* {
        void* p = w + off;
        off += (bytes + 255) & ~(size_t)255;
        return p;
    };
    int* mode   = (int*)alloc(256);
    float* wl1 = (float*)alloc(256 * 4 * 4);
    float* wr1 = (float*)alloc(256 * 4 * 4);
    float* wl2 = (float*)alloc(256 * 4 * 4);
    float* wr2 = (float*)alloc(256 * 4 * 4);
    int* deg    = (int*)alloc(NN * 4);
    int* rowptr = (int*)alloc((NN + 1) * 4);
    int* bsum   = (int*)alloc(NBLK_SCAN * 4);
    int* eorder = (int*)alloc((size_t)EE * 4);
    int* csrc   = (int*)alloc((size_t)EE * 4);
    u16* aw     = (u16*)alloc((size_t)EE * 4 * 2);     // 6.8 MB (reused for layer 2)
    float* el1  = (float*)alloc((size_t)NN * 4 * 4);
    float* er1  = (float*)alloc((size_t)NN * 4 * 4);
    float* el2  = (float*)alloc((size_t)NN * 4 * 4);
    float* er2  = (float*)alloc((size_t)NN * 4 * 4);
    u16* BT1    = (u16*)alloc(256 * 256 * 2);
    u16* BT2    = (u16*)alloc(256 * 256 * 2);
    u16* fs1    = (u16*)alloc((size_t)NN * 256 * 2);   // 25.6 MB
    u16* h1     = (u16*)alloc((size_t)NN * 256 * 2);   // 25.6 MB
    u16* c2     = fs1;   // fs1 dead after k_agg1; c2 = [fs2 | res2]

    // 1: detect + zero deg
    k_detect<<<197, 256, 0, stream>>>((const u16*)h, mode, deg);
    // 2: B-transpose + attn vecs + deg count + edge ranks
    k_prep<<<528 + (EE + 255) / 256, 256, 0, stream>>>(
        W1s, al1, W1d, ar1, W2s, al2, W2d, ar2, Wres2, dst,
        BT1, BT2, wl1, wr1, wl2, wr2, deg, eorder, mode);
    // 3: scan stage 1
    k_scan1<<<NBLK_SCAN, 512, 0, stream>>>(deg, rowptr, bsum);
    // 4: scan finalize (inline bsum prefix) + eler1
    k_scan3_eler1<<<196 + NN / 4, 256, 0, stream>>>(rowptr, bsum,
                                                    h, wl1, wr1, el1, er1, mode);
    // 5: layer-1 weights + CSR scatter (atomic-free)
    k_awgen<<<(EE + 255) / 256, 256, 0, stream>>>(src, dst, eorder, rowptr,
                                                  el1, er1, aw, csrc, 1);
    // 6: layer-1 GEMM
    k_gemm_mfma<<<782, 256, 0, stream>>>(h, 1, BT1, fs1, mode);
    // 7: layer-1 aggregation (weighted gather) + fused eler2
    k_agg1<<<NN / 4, 256, 0, stream>>>(rowptr, csrc, aw, fs1, h, h1,
                                       wl2, wr2, el2, er2, mode);
    // 8: layer-2 fused GEMM [W2s | Wres2]
    k_gemm_mfma<<<782, 256, 0, stream>>>(h1, 0, BT2, c2, mode);
    // 9: layer-2 weights (atomic-free, aw buffer reused)
    k_awgen<<<(EE + 255) / 256, 256, 0, stream>>>(src, dst, eorder, rowptr,
                                                  el2, er2, aw, csrc, 0);
    // 10: layer-2 aggregation + residual + head-mean
    k_agg2<<<NN / 4, 256, 0, stream>>>(rowptr, csrc, aw, c2, d_out, mode);
}